// Round 1
// baseline (783.465 us; speedup 1.0000x reference)
//
#include <hip/hip_runtime.h>

// ---------------------------------------------------------------------------
// MultiHeadsAttention: X[4,2048,1024] -> ctx[4,2048,1024], q[4,16,2048,64],
// k[4,16,2048,64] (q,k post-RoPE). fp32 in/out, bf16 MFMA internally.
// ---------------------------------------------------------------------------

#define B_  4
#define S_  2048
#define H_  16
#define D_  64
#define HID 1024
#define M_  (B_ * S_)          // 8192

typedef __attribute__((ext_vector_type(8))) short    bf16x8;
typedef __attribute__((ext_vector_type(4))) float    f32x4;
typedef __attribute__((ext_vector_type(4))) unsigned short u16x4;
typedef __attribute__((ext_vector_type(8))) unsigned short u16x8;

__device__ __forceinline__ unsigned short f2bf(float f) {
    union { float f; unsigned u; } v; v.f = f;
    unsigned r = v.u + 0x7fffu + ((v.u >> 16) & 1u);
    return (unsigned short)(r >> 16);
}

// ---------------------------------------------------------------------------
// Kernel 1: cast X fp32 -> bf16
// ---------------------------------------------------------------------------
__global__ __launch_bounds__(256) void cast_x_kernel(
    const float* __restrict__ X, unsigned short* __restrict__ Xb)
{
    int i = (blockIdx.x * 256 + threadIdx.x) * 4;
    float4 v = *(const float4*)(X + i);
    u16x4 o;
    o[0] = f2bf(v.x); o[1] = f2bf(v.y); o[2] = f2bf(v.z); o[3] = f2bf(v.w);
    *(u16x4*)(Xb + i) = o;
}

// ---------------------------------------------------------------------------
// Kernel 2: transpose+cast W[k][n] fp32 -> Wt[n][k] bf16  (z selects q/k/v)
// ---------------------------------------------------------------------------
__global__ __launch_bounds__(256) void cast_wt_kernel(
    const float* __restrict__ Wq, const float* __restrict__ Wk,
    const float* __restrict__ Wv, unsigned short* __restrict__ Wt)
{
    __shared__ float tile[64][65];
    int z = blockIdx.z;
    const float* W = (z == 0) ? Wq : ((z == 1) ? Wk : Wv);
    unsigned short* out = Wt + (size_t)z * HID * HID;
    int n0 = blockIdx.x * 64, k0 = blockIdx.y * 64;
    int tx = threadIdx.x & 63, ty0 = threadIdx.x >> 6;
    for (int i = 0; i < 16; i++) {
        int ty = ty0 * 16 + i;
        tile[ty][tx] = W[(size_t)(k0 + ty) * HID + n0 + tx];
    }
    __syncthreads();
    for (int i = 0; i < 16; i++) {
        int ty = ty0 * 16 + i;
        out[(size_t)(n0 + ty) * HID + k0 + tx] = f2bf(tile[tx][ty]);
    }
}

// ---------------------------------------------------------------------------
// Kernel 3: QKV GEMM (bf16 MFMA) + bias + RoPE epilogue.
// grid (M/64, N/64, 3); block 256 = 4 waves, each wave does 32x32.
// z=0: q -> out_q fp32 + Qb bf16 (RoPE applied)
// z=1: k -> out_k fp32 + Kb bf16 (RoPE applied)
// z=2: v -> Vb bf16
// ---------------------------------------------------------------------------
__global__ __launch_bounds__(256) void qkv_gemm_kernel(
    const unsigned short* __restrict__ Xb, const unsigned short* __restrict__ Wt,
    const float* __restrict__ bq, const float* __restrict__ bk,
    const float* __restrict__ bv,
    float* __restrict__ out,      // d_out base
    unsigned short* __restrict__ Qb, unsigned short* __restrict__ Kb,
    unsigned short* __restrict__ Vb)
{
    const size_t Q_OFF = (size_t)B_ * S_ * HID;       // 8388608
    const size_t K_OFF = 2 * Q_OFF;

    int z = blockIdx.z;
    const unsigned short* W = Wt + (size_t)z * HID * HID;
    const float* bias = (z == 0) ? bq : ((z == 1) ? bk : bv);

    int m0 = blockIdx.x * 64, n0 = blockIdx.y * 64;
    int tid = threadIdx.x;
    int wave = tid >> 6, lane = tid & 63;
    int quad = lane >> 4, l15 = lane & 15;
    int wm0 = m0 + (wave >> 1) * 32;
    int wn0 = n0 + (wave & 1) * 32;

    f32x4 acc[2][2] = {};

    for (int k = 0; k < HID; k += 32) {
        bf16x8 a[2], bb[2];
        for (int rt = 0; rt < 2; rt++)
            a[rt] = *(const bf16x8*)(Xb + (size_t)(wm0 + rt * 16 + l15) * HID + k + quad * 8);
        for (int ct = 0; ct < 2; ct++)
            bb[ct] = *(const bf16x8*)(W + (size_t)(wn0 + ct * 16 + l15) * HID + k + quad * 8);
        for (int rt = 0; rt < 2; rt++)
            for (int ct = 0; ct < 2; ct++)
                acc[rt][ct] = __builtin_amdgcn_mfma_f32_16x16x32_bf16(
                    a[rt], bb[ct], acc[rt][ct], 0, 0, 0);
    }

    // epilogue: C/D layout col = lane&15, row = quad*4 + reg
    const float NEG_LN1E4_32 = -0.28782313662425576f;  // -ln(10000)/32
    for (int ct = 0; ct < 2; ct++) {
        int n = wn0 + ct * 16 + l15;
        float bval = bias[n];
        int h = n >> 6, d = n & 63;
        float freq = __expf(NEG_LN1E4_32 * (float)(d >> 1));
        for (int rt = 0; rt < 2; rt++) {
            for (int r = 0; r < 4; r++) {
                int m = wm0 + rt * 16 + quad * 4 + r;
                int b = m >> 11, s = m & (S_ - 1);
                float y = acc[rt][ct][r] + bval;
                size_t o = ((size_t)(b * H_ + h) * S_ + s) * D_ + d;
                if (z < 2) {
                    float ang = (float)s * freq;
                    float c = cosf(ang), sn = sinf(ang);
                    float p = __shfl_xor(y, 1);
                    float yr = ((d & 1) == 0) ? (y * c - p * sn) : (y * c + p * sn);
                    if (z == 0) { out[Q_OFF + o] = yr; Qb[o] = f2bf(yr); }
                    else        { out[K_OFF + o] = yr; Kb[o] = f2bf(yr); }
                } else {
                    Vb[o] = f2bf(y);
                }
            }
        }
    }
}

// ---------------------------------------------------------------------------
// Kernel 4: flash attention. grid (S/64, H, B); block 256 = 4 waves.
// Each wave owns 16 query rows; KV tiles of 64.
// ---------------------------------------------------------------------------
#define SPAD 67
#define PPAD 72

__global__ __launch_bounds__(256) void attn_kernel(
    const unsigned short* __restrict__ Qb, const unsigned short* __restrict__ Kb,
    const unsigned short* __restrict__ Vb, const float* __restrict__ mask,
    float* __restrict__ out)
{
    __shared__ float          s_lds[64][SPAD];
    __shared__ unsigned short p_lds[64][PPAD];
    __shared__ unsigned short vt_lds[64][PPAD];
    __shared__ float m_lds[64], l_lds[64], a_lds[64];

    int q0 = blockIdx.x * 64;
    int h  = blockIdx.y;
    int b  = blockIdx.z;
    int tid = threadIdx.x;
    int wave = tid >> 6, lane = tid & 63;
    int quad = lane >> 4, l15 = lane & 15;

    size_t bh = (size_t)(b * H_ + h) * S_;
    const unsigned short* Qp = Qb + bh * D_;
    const unsigned short* Kp = Kb + bh * D_;
    const unsigned short* Vp = Vb + bh * D_;
    const float* mp = mask + (size_t)b * S_;

    // Q A-fragments, held in registers for the whole KV loop
    bf16x8 qa[2];
    for (int hf = 0; hf < 2; hf++)
        qa[hf] = *(const bf16x8*)(Qp + (size_t)(q0 + wave * 16 + l15) * D_ + hf * 32 + quad * 8);

    f32x4 o[4] = {};

    if (tid < 64) { m_lds[tid] = -1e30f; l_lds[tid] = 0.0f; }
    __syncthreads();

    const float scale = 0.03125f;  // 1/sqrt(1024)

    for (int kv = 0; kv < S_; kv += 64) {
        // stage V tile transposed into LDS: vt_lds[d][kpos]
        {
            int kpos = lane;            // 0..63
            int dblk = wave;            // 0..3 -> d = dblk*16 .. +15
            const unsigned short* vr = Vp + (size_t)(kv + kpos) * D_ + dblk * 16;
            u16x8 v0 = *(const u16x8*)(vr);
            u16x8 v1 = *(const u16x8*)(vr + 8);
            for (int e = 0; e < 8; e++) vt_lds[dblk * 16 + e][kpos] = v0[e];
            for (int e = 0; e < 8; e++) vt_lds[dblk * 16 + 8 + e][kpos] = v1[e];
        }
        __syncthreads();

        // QK^T: 4 column tiles of 16 keys, contraction D=64 in two halves
        f32x4 sacc[4] = {};
        for (int ct = 0; ct < 4; ct++) {
            for (int hf = 0; hf < 2; hf++) {
                bf16x8 kb = *(const bf16x8*)(Kp + (size_t)(kv + ct * 16 + l15) * D_ + hf * 32 + quad * 8);
                sacc[ct] = __builtin_amdgcn_mfma_f32_16x16x32_bf16(qa[hf], kb, sacc[ct], 0, 0, 0);
            }
        }
        // scores -> LDS (scaled + mask)
        for (int ct = 0; ct < 4; ct++) {
            float mk = mp[kv + ct * 16 + l15];
            for (int r = 0; r < 4; r++)
                s_lds[wave * 16 + quad * 4 + r][ct * 16 + l15] = sacc[ct][r] * scale + mk;
        }
        __syncthreads();

        // online softmax: 4 lanes per row, 16 cols each
        int row = wave * 16 + (lane >> 2);
        int c0 = (lane & 3) * 16;
        float lmax = -1e30f;
        for (int i = 0; i < 16; i++) lmax = fmaxf(lmax, s_lds[row][c0 + i]);
        lmax = fmaxf(lmax, __shfl_xor(lmax, 1));
        lmax = fmaxf(lmax, __shfl_xor(lmax, 2));
        float m_old = m_lds[row];
        float m_new = fmaxf(m_old, lmax);
        float lsum = 0.0f;
        for (int i = 0; i < 16; i++) {
            float p = __expf(s_lds[row][c0 + i] - m_new);
            p_lds[row][c0 + i] = f2bf(p);
            lsum += p;
        }
        lsum += __shfl_xor(lsum, 1);
        lsum += __shfl_xor(lsum, 2);
        float alpha = __expf(m_old - m_new);
        if ((lane & 3) == 0) {
            m_lds[row] = m_new;
            l_lds[row] = l_lds[row] * alpha + lsum;
            a_lds[row] = alpha;
        }
        __syncthreads();

        // rescale O and accumulate P·V
        float a4[4];
        for (int r = 0; r < 4; r++) a4[r] = a_lds[wave * 16 + quad * 4 + r];
        for (int ct = 0; ct < 4; ct++)
            for (int r = 0; r < 4; r++) o[ct][r] *= a4[r];

        bf16x8 pa[2];
        for (int hf = 0; hf < 2; hf++)
            pa[hf] = *(const bf16x8*)(&p_lds[wave * 16 + l15][hf * 32 + quad * 8]);
        for (int ct = 0; ct < 4; ct++) {
            for (int hf = 0; hf < 2; hf++) {
                bf16x8 vb = *(const bf16x8*)(&vt_lds[ct * 16 + l15][hf * 32 + quad * 8]);
                o[ct] = __builtin_amdgcn_mfma_f32_16x16x32_bf16(pa[hf], vb, o[ct], 0, 0, 0);
            }
        }
        __syncthreads();  // before next V tile overwrites vt_lds
    }

    // epilogue: ctx[b][s][h*64 + d] = O / l
    for (int ct = 0; ct < 4; ct++) {
        for (int r = 0; r < 4; r++) {
            int row16 = quad * 4 + r;
            int s_abs = q0 + wave * 16 + row16;
            float val = o[ct][r] / l_lds[wave * 16 + row16];
            size_t off = ((size_t)b * S_ + s_abs) * (H_ * D_) + h * D_ + ct * 16 + l15;
            out[off] = val;
        }
    }
}

// ---------------------------------------------------------------------------
extern "C" void kernel_launch(void* const* d_in, const int* in_sizes, int n_in,
                              void* d_out, int out_size, void* d_ws, size_t ws_size,
                              hipStream_t stream)
{
    const float* X    = (const float*)d_in[0];
    const float* Wq   = (const float*)d_in[1];
    const float* bq   = (const float*)d_in[2];
    const float* Wk   = (const float*)d_in[3];
    const float* bk   = (const float*)d_in[4];
    const float* Wv   = (const float*)d_in[5];
    const float* bv   = (const float*)d_in[6];
    const float* mask = (const float*)d_in[7];

    // workspace layout (bytes)
    char* ws = (char*)d_ws;
    unsigned short* Xb = (unsigned short*)(ws);                      // 16 MB
    unsigned short* Wt = (unsigned short*)(ws + 16777216);           //  6 MB
    unsigned short* Qb = (unsigned short*)(ws + 23068672);           // 16 MB
    unsigned short* Kb = (unsigned short*)(ws + 39845888);           // 16 MB
    unsigned short* Vb = (unsigned short*)(ws + 56623104);           // 16 MB

    cast_x_kernel<<<dim3(M_ * HID / 4 / 256), 256, 0, stream>>>(X, Xb);
    cast_wt_kernel<<<dim3(16, 16, 3), 256, 0, stream>>>(Wq, Wk, Wv, Wt);
    qkv_gemm_kernel<<<dim3(M_ / 64, HID / 64, 3), 256, 0, stream>>>(
        Xb, Wt, bq, bk, bv, (float*)d_out, Qb, Kb, Vb);
    attn_kernel<<<dim3(S_ / 64, H_, B_), 256, 0, stream>>>(
        Qb, Kb, Vb, mask, (float*)d_out);
}